// Round 12
// baseline (381.766 us; speedup 1.0000x reference)
//
#include <hip/hip_runtime.h>
#include <math.h>

#define EPS 1e-12f

typedef unsigned short ushort_t;
typedef __attribute__((ext_vector_type(8))) short short8;
typedef __attribute__((ext_vector_type(4))) float f32x4;
typedef __attribute__((ext_vector_type(4))) unsigned short ushort4v;
typedef __attribute__((ext_vector_type(2))) unsigned int uint2v;
typedef __attribute__((ext_vector_type(4))) unsigned int uint32x4;

// ---- workspace layout (float units) ----
#define WS_WB_F 0
#define WS_WO_F 24576
#define WS_TH_F 40960
#define WS_PH_F 1089536
#define WS_G_F  1351680

__device__ __forceinline__ ushort_t f2bf(float f) {
  unsigned int u = __float_as_uint(f);
  u += 0x7fffu + ((u >> 16) & 1u);
  return (ushort_t)(u >> 16);
}
__device__ __forceinline__ float bf2f(ushort_t u) {
  return __uint_as_float(((unsigned int)u) << 16);
}
// cheap bf16x2 pack, round-half-away
__device__ __forceinline__ unsigned int pack_bfrh(float lo, float hi) {
  unsigned int a = __float_as_uint(lo) + 0x8000u;
  unsigned int b = __float_as_uint(hi) + 0x8000u;
  return (a >> 16) | (b & 0xffff0000u);
}
// raw 2^x (VOP1)
__device__ __forceinline__ float exp2_hw(float x) {
  float r;
  asm("v_exp_f32 %0, %1" : "=v"(r) : "v"(x));
  return r;
}

// async 16B global->LDS DMA (LDS dest wave-uniform; global src PER-LANE)
__device__ __forceinline__ void gload_lds16(const ushort_t* g, ushort_t* l) {
  __builtin_amdgcn_global_load_lds(
      (const __attribute__((address_space(1))) unsigned int*)g,
      (__attribute__((address_space(3))) unsigned int*)l, 16, 0, 0);
}

__device__ __forceinline__ float block_reduce_sum(float v, float* red) {
  int t = threadIdx.x;
  red[t] = v;
  __syncthreads();
  #pragma unroll
  for (int s = 128; s > 0; s >>= 1) {
    if (t < s) red[t] += red[t + s];
    __syncthreads();
  }
  float r = red[0];
  __syncthreads();
  return r;
}

// One block per weight: spectral-norm scale, emit bf16 weights in
// MFMA-fragment order. Wo k-axis pi^-1-permuted. Theta additionally
// scaled by log2(e) so attn softmax runs in exp2 domain.
__global__ __launch_bounds__(256) void sn_kernel(
    const float* __restrict__ Wt, const float* __restrict__ Wp,
    const float* __restrict__ Wg, const float* __restrict__ Wo,
    const float* __restrict__ ut, const float* __restrict__ up,
    const float* __restrict__ ug, const float* __restrict__ uo,
    float* __restrict__ ws) {
  __shared__ float red[256];
  __shared__ float ub[256];
  __shared__ float vb[256];
  const float* W; const float* u; int O, Ci;
  switch (blockIdx.x) {
    case 0:  W = Wt; u = ut; O = 32;  Ci = 256; break;
    case 1:  W = Wp; u = up; O = 32;  Ci = 256; break;
    case 2:  W = Wg; u = ug; O = 128; Ci = 256; break;
    default: W = Wo; u = uo; O = 256; Ci = 128; break;
  }
  int t = threadIdx.x;
  if (t < O) ub[t] = u[t];
  __syncthreads();
  float tv = 0.f;
  if (t < Ci) {
    for (int o = 0; o < O; o++) tv += W[o * Ci + t] * ub[o];
  }
  float nt2 = block_reduce_sum((t < Ci) ? tv * tv : 0.f, red);
  float ntn = sqrtf(nt2);
  if (t < Ci) vb[t] = tv / (ntn + EPS);
  __syncthreads();
  float sv = 0.f;
  if (t < O) {
    const float* Wr = W + (size_t)t * Ci;
    for (int c = 0; c < Ci; c += 4) {
      float4 wv = *(const float4*)(Wr + c);
      sv += wv.x * vb[c] + wv.y * vb[c + 1] + wv.z * vb[c + 2] + wv.w * vb[c + 3];
    }
  }
  float ss = block_reduce_sum((t < O) ? sv * sv : 0.f, red);
  float ns = sqrtf(ss);
  float sigma = ss / (ns + EPS);
  float inv = 1.f / sigma;
  if (blockIdx.x == 0) inv *= 1.44269504088896f;   // log2(e) into theta
  int total = O * Ci;
  if (blockIdx.x == 3) {
    // Wo fragment order, k-axis pi^-1-permuted within each 32-chunk.
    ushort_t* dst = (ushort_t*)(ws + WS_WO_F);
    for (int i = t; i < total; i += 256) {
      int o = i >> 7, c = i & 127;
      int oct = o >> 4, l16o = o & 15, kc = c >> 5, cl = c & 31;
      int kap = (cl < 16) ? ((cl >> 2) * 8 + (cl & 3))
                          : (((cl >> 2) & 3) * 8 + 4 + (cl & 3));
      dst[(((kc * 16 + oct) * 64 + (kap >> 3) * 16 + l16o) << 3) + (kap & 7)] =
          f2bf(W[i] * inv);
    }
  } else {
    // proj fragment order: [(mtg*8+kc)*64 + quad*16 + l16]*8 + j
    int base_row = (blockIdx.x == 0) ? 0 : (blockIdx.x == 1 ? 32 : 64);
    ushort_t* dst = (ushort_t*)(ws + WS_WB_F);
    for (int i = t; i < total; i += 256) {
      int o = i >> 8, c = i & 255;
      int og = base_row + o;
      int mtg = og >> 4, l16o = og & 15, kc = c >> 5, qd = (c >> 3) & 3, j = c & 7;
      dst[(((mtg * 8 + kc) * 64 + qd * 16 + l16o) << 3) + j] = f2bf(W[i] * inv);
    }
  }
}

// Fused projection GEMM (R8/R10 LDS version — proven fastest variant).
// phi pi-permuted per 32-key chunk; g written in MFMA A-fragment order.
__global__ __launch_bounds__(256, 2) void proj_mfma(
    const float* __restrict__ x, const ushort_t* __restrict__ wb,
    ushort_t* __restrict__ theta_b, ushort_t* __restrict__ phi_b,
    ushort_t* __restrict__ g_fb) {
  __shared__ ushort_t xb[128 * 264];
  const int t = threadIdx.x;
  const int n = blockIdx.y;
  const int l0 = blockIdx.x * 128;
  const float* xn = x + ((size_t)n * 256) * 4096 + l0;
  {
    const int lrel = t & 127;
    const int half = t >> 7;
    #pragma unroll 4
    for (int ch = 0; ch < 16; ++ch) {
      int chunk = half * 16 + ch;
      short8 v;
      #pragma unroll
      for (int j = 0; j < 8; ++j) {
        float f = xn[(size_t)(chunk * 8 + j) * 4096 + lrel];
        v[j] = (short)f2bf(f);
      }
      *(short8*)(&xb[lrel * 264 + chunk * 8]) = v;
    }
  }
  __syncthreads();
  const int w = t >> 6;
  const int lane = t & 63;
  const int quad = lane >> 4;
  const int l16 = lane & 15;
  const int rowA = (w * 16 + l16) * 264;
  const int rowB = (64 + w * 16 + l16) * 264;
  const int hd = blockIdx.x;
  #pragma unroll 1
  for (int pass = 0; pass < 2; ++pass) {
    f32x4 accA[6], accB[6];
    #pragma unroll
    for (int i = 0; i < 6; ++i) {
      accA[i] = (f32x4){0.f, 0.f, 0.f, 0.f};
      accB[i] = (f32x4){0.f, 0.f, 0.f, 0.f};
    }
    #pragma unroll
    for (int kc = 0; kc < 8; ++kc) {
      short8 bA = *(const short8*)(&xb[rowA + kc * 32 + quad * 8]);
      short8 bB = *(const short8*)(&xb[rowB + kc * 32 + quad * 8]);
      #pragma unroll
      for (int mt = 0; mt < 6; ++mt) {
        int mtg = pass * 6 + mt;
        short8 aW = *(const short8*)(wb + (((size_t)(mtg * 8 + kc) * 64 + lane) << 3));
        accA[mt] = __builtin_amdgcn_mfma_f32_16x16x32_bf16(aW, bA, accA[mt], 0, 0, 0);
        accB[mt] = __builtin_amdgcn_mfma_f32_16x16x32_bf16(aW, bB, accB[mt], 0, 0, 0);
      }
    }
    #pragma unroll
    for (int mt = 0; mt < 6; ++mt) {
      int mtg = pass * 6 + mt;
      if (mtg < 2) {
        int lA = l0 + w * 16 + l16;
        ushort4v vA, vB;
        #pragma unroll
        for (int r = 0; r < 4; ++r) { vA[r] = f2bf(accA[mt][r]); vB[r] = f2bf(accB[mt][r]); }
        *(ushort4v*)(theta_b + ((size_t)n * 4096 + lA) * 32 + mtg * 16 + quad * 4) = vA;
        *(ushort4v*)(theta_b + ((size_t)n * 4096 + lA + 64) * 32 + mtg * 16 + quad * 4) = vB;
      } else {
        float pm[4];
        #pragma unroll
        for (int r = 0; r < 4; ++r) {
          float v = fmaxf(accA[mt][r], accB[mt][r]);
          v = fmaxf(v, __shfl_xor(v, 1));
          pm[r] = v;
        }
        if ((l16 & 1) == 0) {
          int rr = l16 >> 1;
          if (mtg < 4) {
            // pi-permuted phi row: kg = w*8+rr -> pi(kg)
            int mp = hd * 32 + ((rr & 4) ? 16 : 0) + w * 4 + (rr & 3);
            ushort4v vv;
            #pragma unroll
            for (int r = 0; r < 4; ++r) vv[r] = f2bf(pm[r]);
            *(ushort4v*)(phi_b + ((size_t)n * 1024 + mp) * 32 + (mtg - 2) * 16 + quad * 4) = vv;
          } else {
            // g in A-fragment order: frag (hd, j = mtg-4), slot = w*16+quad*4+r
            size_t fb = (size_t)n * 131072 +
                        (size_t)((hd * 8 + (mtg - 4)) * 64 + w * 16 + quad * 4) * 8 + rr;
            #pragma unroll
            for (int r = 0; r < 4; ++r)
              g_fb[fb + (size_t)r * 8] = f2bf(pm[r]);
          }
        }
      }
    }
  }
}

// Flash attention v10: v9 main loop unchanged; epilogue now stages Wo
// through the freed gbuf in two contiguous 32KB kc-halves (L2 Wo traffic
// /4: 1MB -> 256KB per CU), acc2[16] accumulated across halves.
__global__ __launch_bounds__(256, 4) void attn_mfma(
    const float* __restrict__ x,
    const ushort_t* __restrict__ theta_b,
    const ushort_t* __restrict__ phi_b,
    const ushort_t* __restrict__ g_fb,
    const ushort_t* __restrict__ Wo_fb,
    const float* __restrict__ gamma_p,
    float* __restrict__ out) {
  // [0, 32768): gbuf (32 frags x 1KB) | [0, 34816): outb overlay
  __shared__ __align__(16) unsigned char smem[34816];
  ushort_t* gbuf = (ushort_t*)smem;
  ushort_t* outb = (ushort_t*)smem;

  const int t = threadIdx.x;
  const int w = t >> 6;
  const int lane = t & 63;
  const int quad = lane >> 4;
  const int l16 = lane & 15;

  // XCD swizzle: grid 1024 -> 8 XCDs x 128; 2 images per XCD L2.
  const int flat = blockIdx.y * 64 + blockIdx.x;
  const int nf = ((flat & 7) << 7) | (flat >> 3);
  const int n = nf >> 6;
  const int l0 = (nf & 63) << 6;
  const int lq = l0 + w * 16;

  const short8 bth = *(const short8*)(theta_b + ((size_t)n * 4096 + lq + l16) * 32 + quad * 8);
  const ushort_t* phiN = phi_b + (size_t)n * 1024 * 32;
  const ushort_t* gN   = g_fb + (size_t)n * 131072;

  f32x4 oacc[8];
  #pragma unroll
  for (int j = 0; j < 8; ++j) oacc[j] = (f32x4){0.f, 0.f, 0.f, 0.f};
  float M = -3.0e38f, L = 0.f;
  unsigned int pk[16];

  // wave w stages fragments idx = w*8 .. w*8+7; each lane fetches ITS 16B
  auto STAGE = [&](int mc) {
    const ushort_t* src = gN + (size_t)mc * 16384 + w * 8 * 512 + lane * 8;
    ushort_t* dst = gbuf + w * 8 * 512;
    #pragma unroll
    for (int b = 0; b < 8; ++b)
      gload_lds16(src + b * 512, dst + b * 512);
  };

  auto QKSM = [&](int mc) {
    const int m0 = mc * 128;
    const f32x4 z = (f32x4){0.f, 0.f, 0.f, 0.f};
    f32x4 st[8];
    #pragma unroll
    for (int i = 0; i < 8; ++i) {
      short8 aph = *(const short8*)(phiN + (size_t)(m0 + i * 16 + l16) * 32 + quad * 8);
      st[i] = __builtin_amdgcn_mfma_f32_16x16x32_bf16(aph, bth, z, 0, 0, 0);
    }
    // lane-local partial max (no cross-lane)
    f32x4 a0 = st[0], a1 = st[1], a2 = st[2], a3 = st[3];
    #pragma unroll
    for (int r = 0; r < 4; ++r) {
      a0[r] = fmaxf(a0[r], st[4][r]); a1[r] = fmaxf(a1[r], st[5][r]);
      a2[r] = fmaxf(a2[r], st[6][r]); a3[r] = fmaxf(a3[r], st[7][r]);
    }
    #pragma unroll
    for (int r = 0; r < 4; ++r) { a0[r] = fmaxf(a0[r], a2[r]); a1[r] = fmaxf(a1[r], a3[r]); }
    float mlane = fmaxf(fmaxf(fmaxf(a0[0], a1[0]), fmaxf(a0[1], a1[1])),
                        fmaxf(fmaxf(a0[2], a1[2]), fmaxf(a0[3], a1[3])));
    // defer-max: only reduce cross-lane + rescale when the bound grows
    if (!__all(mlane <= M + 8.0f)) {
      float mx = fmaxf(mlane, __shfl_xor(mlane, 16));
      mx = fmaxf(mx, __shfl_xor(mx, 32));
      float nm = fmaxf(M, mx);
      float al = exp2_hw(M - nm);
      M = nm;
      L *= al;
      #pragma unroll
      for (int j = 0; j < 8; ++j) {
        #pragma unroll
        for (int r = 0; r < 4; ++r) oacc[j][r] *= al;
      }
    }
    #pragma unroll
    for (int i = 0; i < 8; ++i) {
      #pragma unroll
      for (int r = 0; r < 4; ++r) st[i][r] = exp2_hw(st[i][r] - M);
    }
    f32x4 s0 = st[0], s1 = st[1];
    #pragma unroll
    for (int r = 0; r < 4; ++r) {
      s0[r] += st[2][r] + st[4][r] + st[6][r];
      s1[r] += st[3][r] + st[5][r] + st[7][r];
    }
    L += (s0[0] + s1[0]) + (s0[1] + s1[1]) + (s0[2] + s1[2]) + (s0[3] + s1[3]);
    #pragma unroll
    for (int i = 0; i < 8; ++i) {
      pk[2 * i]     = pack_bfrh(st[i][0], st[i][1]);
      pk[2 * i + 1] = pack_bfrh(st[i][2], st[i][3]);
    }
  };

  auto PV = [&]() {
    __builtin_amdgcn_s_setprio(1);
    #pragma unroll
    for (int s = 0; s < 4; ++s) {
      uint32x4 u = {pk[4 * s], pk[4 * s + 1], pk[4 * s + 2], pk[4 * s + 3]};
      short8 pb = __builtin_bit_cast(short8, u);
      #pragma unroll
      for (int j = 0; j < 8; ++j) {
        short8 gf = *(const short8*)(gbuf + (size_t)(s * 8 + j) * 512 + lane * 8);
        oacc[j] = __builtin_amdgcn_mfma_f32_16x16x32_bf16(gf, pb, oacc[j], 0, 0, 0);
      }
    }
    __builtin_amdgcn_s_setprio(0);
  };

  // prologue: stage chunk 0, compute its scores while DMA flies
  STAGE(0);
  QKSM(0);
  __syncthreads();            // drains DMA -> gbuf = chunk 0
  #pragma unroll 1
  for (int mc = 0; mc < 8; ++mc) {
    PV();                     // consume gbuf (chunk mc)
    if (mc < 7) {
      __syncthreads();        // all waves done reading gbuf
      STAGE(mc + 1);          // overwrite; latency hides under QKSM
      QKSM(mc + 1);
      __syncthreads();        // publish chunk mc+1
    }
  }
  __syncthreads();            // all PV done; gbuf free for Wo staging

  // ---- cross-quad L reduce ----
  L += __shfl_xor(L, 16);
  L += __shfl_xor(L, 32);
  const float invL = 1.f / L;

  // ---- epilogue: Wo staged via gbuf in two 32KB kc-halves ----
  f32x4 acc2[16];
  #pragma unroll
  for (int i = 0; i < 16; ++i) acc2[i] = (f32x4){0.f, 0.f, 0.f, 0.f};
  #pragma unroll 1
  for (int h = 0; h < 2; ++h) {
    // stage Wo frags f = h*32 .. h*32+31 (contiguous 32KB, kc-major)
    {
      const ushort_t* src = Wo_fb + (size_t)h * 16384 + w * 8 * 512 + lane * 8;
      ushort_t* dst = gbuf + w * 8 * 512;
      #pragma unroll
      for (int b = 0; b < 8; ++b)
        gload_lds16(src + b * 512, dst + b * 512);
    }
    __syncthreads();          // drain DMA -> gbuf = Wo half h
    #pragma unroll
    for (int kcl = 0; kcl < 2; ++kcl) {
      int kc = h * 2 + kcl;
      uint32x4 u;
      u[0] = pack_bfrh(oacc[2 * kc][0] * invL, oacc[2 * kc][1] * invL);
      u[1] = pack_bfrh(oacc[2 * kc][2] * invL, oacc[2 * kc][3] * invL);
      u[2] = pack_bfrh(oacc[2 * kc + 1][0] * invL, oacc[2 * kc + 1][1] * invL);
      u[3] = pack_bfrh(oacc[2 * kc + 1][2] * invL, oacc[2 * kc + 1][3] * invL);
      short8 aO = __builtin_bit_cast(short8, u);
      #pragma unroll
      for (int oct = 0; oct < 16; ++oct) {
        short8 bw = *(const short8*)(gbuf + (size_t)(kcl * 16 + oct) * 512 + lane * 8);
        acc2[oct] = __builtin_amdgcn_mfma_f32_16x16x32_bf16(aO, bw, acc2[oct], 0, 0, 0);
      }
    }
    __syncthreads();          // all waves done reading gbuf (next overwrite)
  }
  // write outb (overlays gbuf; guarded by the barrier above)
  #pragma unroll
  for (int oct = 0; oct < 16; ++oct) {
    uint2v p2;
    p2[0] = pack_bfrh(acc2[oct][0], acc2[oct][1]);
    p2[1] = pack_bfrh(acc2[oct][2], acc2[oct][3]);
    *(uint2v*)(&outb[(oct * 16 + l16) * 68 + w * 16 + quad * 4]) = p2;
  }
  __syncthreads();
  // ---- residual + coalesced stores (64 cols) ----
  {
    const float gm = gamma_p[0];
    const int oc = (t >> 4);
    const int lch = (t & 15) * 4;
    #pragma unroll
    for (int ocg = 0; ocg < 16; ++ocg) {
      int row = ocg * 16 + oc;
      ushort4v ov = *(const ushort4v*)(&outb[row * 68 + lch]);
      const float* xp = x + ((size_t)n * 256 + row) * 4096 + l0 + lch;
      float* op = out + ((size_t)n * 256 + row) * 4096 + l0 + lch;
      float4 xv = *(const float4*)xp;
      float4 v;
      v.x = xv.x + gm * bf2f(ov[0]);
      v.y = xv.y + gm * bf2f(ov[1]);
      v.z = xv.z + gm * bf2f(ov[2]);
      v.w = xv.w + gm * bf2f(ov[3]);
      *(float4*)op = v;
    }
  }
}

extern "C" void kernel_launch(void* const* d_in, const int* in_sizes, int n_in,
                              void* d_out, int out_size, void* d_ws, size_t ws_size,
                              hipStream_t stream) {
  const float* x  = (const float*)d_in[0];
  const float* Wt = (const float*)d_in[1];
  const float* Wp = (const float*)d_in[2];
  const float* Wg = (const float*)d_in[3];
  const float* Wo = (const float*)d_in[4];
  const float* ut = (const float*)d_in[5];
  const float* up = (const float*)d_in[6];
  const float* ug = (const float*)d_in[7];
  const float* uo = (const float*)d_in[8];
  const float* gamma = (const float*)d_in[9];
  float* ws  = (float*)d_ws;
  float* out = (float*)d_out;

  ushort_t* wb      = (ushort_t*)(ws + WS_WB_F);
  ushort_t* Wo_b    = (ushort_t*)(ws + WS_WO_F);
  ushort_t* theta_b = (ushort_t*)(ws + WS_TH_F);
  ushort_t* phi_b   = (ushort_t*)(ws + WS_PH_F);
  ushort_t* g_fb    = (ushort_t*)(ws + WS_G_F);

  sn_kernel<<<4, 256, 0, stream>>>(Wt, Wp, Wg, Wo, ut, up, ug, uo, ws);
  proj_mfma<<<dim3(32, 16), 256, 0, stream>>>(x, wb, theta_b, phi_b, g_fb);
  attn_mfma<<<dim3(64, 16), 256, 0, stream>>>(x, theta_b, phi_b, g_fb, Wo_b, gamma, out);
}

// Round 13
// 201.036 us; speedup vs baseline: 1.8990x; 1.8990x over previous
//
#include <hip/hip_runtime.h>
#include <math.h>

#define EPS 1e-12f

typedef unsigned short ushort_t;
typedef __attribute__((ext_vector_type(8))) short short8;
typedef __attribute__((ext_vector_type(4))) float f32x4;
typedef __attribute__((ext_vector_type(4))) unsigned short ushort4v;
typedef __attribute__((ext_vector_type(2))) unsigned int uint2v;
typedef __attribute__((ext_vector_type(4))) unsigned int uint32x4;

// ---- workspace layout (float units) ----
#define WS_WB_F 0
#define WS_WO_F 24576
#define WS_TH_F 40960
#define WS_PH_F 1089536
#define WS_G_F  1351680

__device__ __forceinline__ ushort_t f2bf(float f) {
  unsigned int u = __float_as_uint(f);
  u += 0x7fffu + ((u >> 16) & 1u);
  return (ushort_t)(u >> 16);
}
__device__ __forceinline__ float bf2f(ushort_t u) {
  return __uint_as_float(((unsigned int)u) << 16);
}
// cheap bf16x2 pack, round-half-away
__device__ __forceinline__ unsigned int pack_bfrh(float lo, float hi) {
  unsigned int a = __float_as_uint(lo) + 0x8000u;
  unsigned int b = __float_as_uint(hi) + 0x8000u;
  return (a >> 16) | (b & 0xffff0000u);
}
// raw 2^x (VOP1)
__device__ __forceinline__ float exp2_hw(float x) {
  float r;
  asm("v_exp_f32 %0, %1" : "=v"(r) : "v"(x));
  return r;
}

// async 16B global->LDS DMA (LDS dest wave-uniform; global src PER-LANE)
__device__ __forceinline__ void gload_lds16(const ushort_t* g, ushort_t* l) {
  __builtin_amdgcn_global_load_lds(
      (const __attribute__((address_space(1))) unsigned int*)g,
      (__attribute__((address_space(3))) unsigned int*)l, 16, 0, 0);
}

__device__ __forceinline__ float block_reduce_sum(float v, float* red) {
  int t = threadIdx.x;
  red[t] = v;
  __syncthreads();
  #pragma unroll
  for (int s = 128; s > 0; s >>= 1) {
    if (t < s) red[t] += red[t + s];
    __syncthreads();
  }
  float r = red[0];
  __syncthreads();
  return r;
}

// One block per weight: spectral-norm scale, emit bf16 weights in
// MFMA-fragment order. Wo k-axis pi^-1-permuted. Theta additionally
// scaled by log2(e) so attn softmax runs in exp2 domain.
__global__ __launch_bounds__(256) void sn_kernel(
    const float* __restrict__ Wt, const float* __restrict__ Wp,
    const float* __restrict__ Wg, const float* __restrict__ Wo,
    const float* __restrict__ ut, const float* __restrict__ up,
    const float* __restrict__ ug, const float* __restrict__ uo,
    float* __restrict__ ws) {
  __shared__ float red[256];
  __shared__ float ub[256];
  __shared__ float vb[256];
  const float* W; const float* u; int O, Ci;
  switch (blockIdx.x) {
    case 0:  W = Wt; u = ut; O = 32;  Ci = 256; break;
    case 1:  W = Wp; u = up; O = 32;  Ci = 256; break;
    case 2:  W = Wg; u = ug; O = 128; Ci = 256; break;
    default: W = Wo; u = uo; O = 256; Ci = 128; break;
  }
  int t = threadIdx.x;
  if (t < O) ub[t] = u[t];
  __syncthreads();
  float tv = 0.f;
  if (t < Ci) {
    for (int o = 0; o < O; o++) tv += W[o * Ci + t] * ub[o];
  }
  float nt2 = block_reduce_sum((t < Ci) ? tv * tv : 0.f, red);
  float ntn = sqrtf(nt2);
  if (t < Ci) vb[t] = tv / (ntn + EPS);
  __syncthreads();
  float sv = 0.f;
  if (t < O) {
    const float* Wr = W + (size_t)t * Ci;
    for (int c = 0; c < Ci; c += 4) {
      float4 wv = *(const float4*)(Wr + c);
      sv += wv.x * vb[c] + wv.y * vb[c + 1] + wv.z * vb[c + 2] + wv.w * vb[c + 3];
    }
  }
  float ss = block_reduce_sum((t < O) ? sv * sv : 0.f, red);
  float ns = sqrtf(ss);
  float sigma = ss / (ns + EPS);
  float inv = 1.f / sigma;
  if (blockIdx.x == 0) inv *= 1.44269504088896f;   // log2(e) into theta
  int total = O * Ci;
  if (blockIdx.x == 3) {
    // Wo fragment order, k-axis pi^-1-permuted within each 32-chunk.
    ushort_t* dst = (ushort_t*)(ws + WS_WO_F);
    for (int i = t; i < total; i += 256) {
      int o = i >> 7, c = i & 127;
      int oct = o >> 4, l16o = o & 15, kc = c >> 5, cl = c & 31;
      int kap = (cl < 16) ? ((cl >> 2) * 8 + (cl & 3))
                          : (((cl >> 2) & 3) * 8 + 4 + (cl & 3));
      dst[(((kc * 16 + oct) * 64 + (kap >> 3) * 16 + l16o) << 3) + (kap & 7)] =
          f2bf(W[i] * inv);
    }
  } else {
    // proj fragment order: [(mtg*8+kc)*64 + quad*16 + l16]*8 + j
    int base_row = (blockIdx.x == 0) ? 0 : (blockIdx.x == 1 ? 32 : 64);
    ushort_t* dst = (ushort_t*)(ws + WS_WB_F);
    for (int i = t; i < total; i += 256) {
      int o = i >> 8, c = i & 255;
      int og = base_row + o;
      int mtg = og >> 4, l16o = og & 15, kc = c >> 5, qd = (c >> 3) & 3, j = c & 7;
      dst[(((mtg * 8 + kc) * 64 + qd * 16 + l16o) << 3) + j] = f2bf(W[i] * inv);
    }
  }
}

// Fused projection GEMM (R8/R10 LDS version — proven fastest variant).
// phi pi-permuted per 32-key chunk; g written in MFMA A-fragment order.
__global__ __launch_bounds__(256, 2) void proj_mfma(
    const float* __restrict__ x, const ushort_t* __restrict__ wb,
    ushort_t* __restrict__ theta_b, ushort_t* __restrict__ phi_b,
    ushort_t* __restrict__ g_fb) {
  __shared__ ushort_t xb[128 * 264];
  const int t = threadIdx.x;
  const int n = blockIdx.y;
  const int l0 = blockIdx.x * 128;
  const float* xn = x + ((size_t)n * 256) * 4096 + l0;
  {
    const int lrel = t & 127;
    const int half = t >> 7;
    #pragma unroll 4
    for (int ch = 0; ch < 16; ++ch) {
      int chunk = half * 16 + ch;
      short8 v;
      #pragma unroll
      for (int j = 0; j < 8; ++j) {
        float f = xn[(size_t)(chunk * 8 + j) * 4096 + lrel];
        v[j] = (short)f2bf(f);
      }
      *(short8*)(&xb[lrel * 264 + chunk * 8]) = v;
    }
  }
  __syncthreads();
  const int w = t >> 6;
  const int lane = t & 63;
  const int quad = lane >> 4;
  const int l16 = lane & 15;
  const int rowA = (w * 16 + l16) * 264;
  const int rowB = (64 + w * 16 + l16) * 264;
  const int hd = blockIdx.x;
  #pragma unroll 1
  for (int pass = 0; pass < 2; ++pass) {
    f32x4 accA[6], accB[6];
    #pragma unroll
    for (int i = 0; i < 6; ++i) {
      accA[i] = (f32x4){0.f, 0.f, 0.f, 0.f};
      accB[i] = (f32x4){0.f, 0.f, 0.f, 0.f};
    }
    #pragma unroll
    for (int kc = 0; kc < 8; ++kc) {
      short8 bA = *(const short8*)(&xb[rowA + kc * 32 + quad * 8]);
      short8 bB = *(const short8*)(&xb[rowB + kc * 32 + quad * 8]);
      #pragma unroll
      for (int mt = 0; mt < 6; ++mt) {
        int mtg = pass * 6 + mt;
        short8 aW = *(const short8*)(wb + (((size_t)(mtg * 8 + kc) * 64 + lane) << 3));
        accA[mt] = __builtin_amdgcn_mfma_f32_16x16x32_bf16(aW, bA, accA[mt], 0, 0, 0);
        accB[mt] = __builtin_amdgcn_mfma_f32_16x16x32_bf16(aW, bB, accB[mt], 0, 0, 0);
      }
    }
    #pragma unroll
    for (int mt = 0; mt < 6; ++mt) {
      int mtg = pass * 6 + mt;
      if (mtg < 2) {
        int lA = l0 + w * 16 + l16;
        ushort4v vA, vB;
        #pragma unroll
        for (int r = 0; r < 4; ++r) { vA[r] = f2bf(accA[mt][r]); vB[r] = f2bf(accB[mt][r]); }
        *(ushort4v*)(theta_b + ((size_t)n * 4096 + lA) * 32 + mtg * 16 + quad * 4) = vA;
        *(ushort4v*)(theta_b + ((size_t)n * 4096 + lA + 64) * 32 + mtg * 16 + quad * 4) = vB;
      } else {
        float pm[4];
        #pragma unroll
        for (int r = 0; r < 4; ++r) {
          float v = fmaxf(accA[mt][r], accB[mt][r]);
          v = fmaxf(v, __shfl_xor(v, 1));
          pm[r] = v;
        }
        if ((l16 & 1) == 0) {
          int rr = l16 >> 1;
          if (mtg < 4) {
            // pi-permuted phi row: kg = w*8+rr -> pi(kg)
            int mp = hd * 32 + ((rr & 4) ? 16 : 0) + w * 4 + (rr & 3);
            ushort4v vv;
            #pragma unroll
            for (int r = 0; r < 4; ++r) vv[r] = f2bf(pm[r]);
            *(ushort4v*)(phi_b + ((size_t)n * 1024 + mp) * 32 + (mtg - 2) * 16 + quad * 4) = vv;
          } else {
            // g in A-fragment order: frag (hd, j = mtg-4), slot = w*16+quad*4+r
            size_t fb = (size_t)n * 131072 +
                        (size_t)((hd * 8 + (mtg - 4)) * 64 + w * 16 + quad * 4) * 8 + rr;
            #pragma unroll
            for (int r = 0; r < 4; ++r)
              g_fb[fb + (size_t)r * 8] = f2bf(pm[r]);
          }
        }
      }
    }
  }
}

// Flash attention v10b: v9 main loop; Wo-staged epilogue FULLY UNROLLED
// (R12 bug: runtime-indexed oacc under "#pragma unroll 1" sent
// accumulators to scratch — all indices are now compile-time literals).
__global__ __launch_bounds__(256, 4) void attn_mfma(
    const float* __restrict__ x,
    const ushort_t* __restrict__ theta_b,
    const ushort_t* __restrict__ phi_b,
    const ushort_t* __restrict__ g_fb,
    const ushort_t* __restrict__ Wo_fb,
    const float* __restrict__ gamma_p,
    float* __restrict__ out) {
  // [0, 32768): gbuf (32 frags x 1KB) | [0, 34816): outb overlay
  __shared__ __align__(16) unsigned char smem[34816];
  ushort_t* gbuf = (ushort_t*)smem;
  ushort_t* outb = (ushort_t*)smem;

  const int t = threadIdx.x;
  const int w = t >> 6;
  const int lane = t & 63;
  const int quad = lane >> 4;
  const int l16 = lane & 15;

  // XCD swizzle: grid 1024 -> 8 XCDs x 128; 2 images per XCD L2.
  const int flat = blockIdx.y * 64 + blockIdx.x;
  const int nf = ((flat & 7) << 7) | (flat >> 3);
  const int n = nf >> 6;
  const int l0 = (nf & 63) << 6;
  const int lq = l0 + w * 16;

  const short8 bth = *(const short8*)(theta_b + ((size_t)n * 4096 + lq + l16) * 32 + quad * 8);
  const ushort_t* phiN = phi_b + (size_t)n * 1024 * 32;
  const ushort_t* gN   = g_fb + (size_t)n * 131072;

  f32x4 oacc[8];
  #pragma unroll
  for (int j = 0; j < 8; ++j) oacc[j] = (f32x4){0.f, 0.f, 0.f, 0.f};
  float M = -3.0e38f, L = 0.f;
  unsigned int pk[16];

  // wave w stages fragments idx = w*8 .. w*8+7; each lane fetches ITS 16B
  auto STAGE = [&](int mc) {
    const ushort_t* src = gN + (size_t)mc * 16384 + w * 8 * 512 + lane * 8;
    ushort_t* dst = gbuf + w * 8 * 512;
    #pragma unroll
    for (int b = 0; b < 8; ++b)
      gload_lds16(src + b * 512, dst + b * 512);
  };

  auto QKSM = [&](int mc) {
    const int m0 = mc * 128;
    const f32x4 z = (f32x4){0.f, 0.f, 0.f, 0.f};
    f32x4 st[8];
    #pragma unroll
    for (int i = 0; i < 8; ++i) {
      short8 aph = *(const short8*)(phiN + (size_t)(m0 + i * 16 + l16) * 32 + quad * 8);
      st[i] = __builtin_amdgcn_mfma_f32_16x16x32_bf16(aph, bth, z, 0, 0, 0);
    }
    // lane-local partial max (no cross-lane)
    f32x4 a0 = st[0], a1 = st[1], a2 = st[2], a3 = st[3];
    #pragma unroll
    for (int r = 0; r < 4; ++r) {
      a0[r] = fmaxf(a0[r], st[4][r]); a1[r] = fmaxf(a1[r], st[5][r]);
      a2[r] = fmaxf(a2[r], st[6][r]); a3[r] = fmaxf(a3[r], st[7][r]);
    }
    #pragma unroll
    for (int r = 0; r < 4; ++r) { a0[r] = fmaxf(a0[r], a2[r]); a1[r] = fmaxf(a1[r], a3[r]); }
    float mlane = fmaxf(fmaxf(fmaxf(a0[0], a1[0]), fmaxf(a0[1], a1[1])),
                        fmaxf(fmaxf(a0[2], a1[2]), fmaxf(a0[3], a1[3])));
    // defer-max: only reduce cross-lane + rescale when the bound grows
    if (!__all(mlane <= M + 8.0f)) {
      float mx = fmaxf(mlane, __shfl_xor(mlane, 16));
      mx = fmaxf(mx, __shfl_xor(mx, 32));
      float nm = fmaxf(M, mx);
      float al = exp2_hw(M - nm);
      M = nm;
      L *= al;
      #pragma unroll
      for (int j = 0; j < 8; ++j) {
        #pragma unroll
        for (int r = 0; r < 4; ++r) oacc[j][r] *= al;
      }
    }
    #pragma unroll
    for (int i = 0; i < 8; ++i) {
      #pragma unroll
      for (int r = 0; r < 4; ++r) st[i][r] = exp2_hw(st[i][r] - M);
    }
    f32x4 s0 = st[0], s1 = st[1];
    #pragma unroll
    for (int r = 0; r < 4; ++r) {
      s0[r] += st[2][r] + st[4][r] + st[6][r];
      s1[r] += st[3][r] + st[5][r] + st[7][r];
    }
    L += (s0[0] + s1[0]) + (s0[1] + s1[1]) + (s0[2] + s1[2]) + (s0[3] + s1[3]);
    #pragma unroll
    for (int i = 0; i < 8; ++i) {
      pk[2 * i]     = pack_bfrh(st[i][0], st[i][1]);
      pk[2 * i + 1] = pack_bfrh(st[i][2], st[i][3]);
    }
  };

  auto PV = [&]() {
    __builtin_amdgcn_s_setprio(1);
    #pragma unroll
    for (int s = 0; s < 4; ++s) {
      uint32x4 u = {pk[4 * s], pk[4 * s + 1], pk[4 * s + 2], pk[4 * s + 3]};
      short8 pb = __builtin_bit_cast(short8, u);
      #pragma unroll
      for (int j = 0; j < 8; ++j) {
        short8 gf = *(const short8*)(gbuf + (size_t)(s * 8 + j) * 512 + lane * 8);
        oacc[j] = __builtin_amdgcn_mfma_f32_16x16x32_bf16(gf, pb, oacc[j], 0, 0, 0);
      }
    }
    __builtin_amdgcn_s_setprio(0);
  };

  // prologue: stage chunk 0, compute its scores while DMA flies
  STAGE(0);
  QKSM(0);
  __syncthreads();            // drains DMA -> gbuf = chunk 0
  #pragma unroll 1
  for (int mc = 0; mc < 8; ++mc) {
    PV();                     // consume gbuf (chunk mc)
    if (mc < 7) {
      __syncthreads();        // all waves done reading gbuf
      STAGE(mc + 1);          // overwrite; latency hides under QKSM
      QKSM(mc + 1);
      __syncthreads();        // publish chunk mc+1
    }
  }
  __syncthreads();            // all PV done; gbuf free for Wo staging

  // ---- cross-quad L reduce ----
  L += __shfl_xor(L, 16);
  L += __shfl_xor(L, 32);
  const float invL = 1.f / L;

  // ---- epilogue: Wo staged via gbuf, fully unrolled (all idx literal) ----
  f32x4 acc2[16];
  #pragma unroll
  for (int i = 0; i < 16; ++i) acc2[i] = (f32x4){0.f, 0.f, 0.f, 0.f};

  // aO fragments (computed up front, compile-time oacc indices)
  short8 aO0, aO1, aO2, aO3;
  {
    uint32x4 u;
    u[0] = pack_bfrh(oacc[0][0] * invL, oacc[0][1] * invL);
    u[1] = pack_bfrh(oacc[0][2] * invL, oacc[0][3] * invL);
    u[2] = pack_bfrh(oacc[1][0] * invL, oacc[1][1] * invL);
    u[3] = pack_bfrh(oacc[1][2] * invL, oacc[1][3] * invL);
    aO0 = __builtin_bit_cast(short8, u);
    u[0] = pack_bfrh(oacc[2][0] * invL, oacc[2][1] * invL);
    u[1] = pack_bfrh(oacc[2][2] * invL, oacc[2][3] * invL);
    u[2] = pack_bfrh(oacc[3][0] * invL, oacc[3][1] * invL);
    u[3] = pack_bfrh(oacc[3][2] * invL, oacc[3][3] * invL);
    aO1 = __builtin_bit_cast(short8, u);
    u[0] = pack_bfrh(oacc[4][0] * invL, oacc[4][1] * invL);
    u[1] = pack_bfrh(oacc[4][2] * invL, oacc[4][3] * invL);
    u[2] = pack_bfrh(oacc[5][0] * invL, oacc[5][1] * invL);
    u[3] = pack_bfrh(oacc[5][2] * invL, oacc[5][3] * invL);
    aO2 = __builtin_bit_cast(short8, u);
    u[0] = pack_bfrh(oacc[6][0] * invL, oacc[6][1] * invL);
    u[1] = pack_bfrh(oacc[6][2] * invL, oacc[6][3] * invL);
    u[2] = pack_bfrh(oacc[7][0] * invL, oacc[7][1] * invL);
    u[3] = pack_bfrh(oacc[7][2] * invL, oacc[7][3] * invL);
    aO3 = __builtin_bit_cast(short8, u);
  }

  // half 0: Wo frags 0..31 (kc 0,1)
  {
    const ushort_t* src = Wo_fb + w * 8 * 512 + lane * 8;
    ushort_t* dst = gbuf + w * 8 * 512;
    #pragma unroll
    for (int b = 0; b < 8; ++b)
      gload_lds16(src + b * 512, dst + b * 512);
  }
  __syncthreads();
  #pragma unroll
  for (int oct = 0; oct < 16; ++oct) {
    short8 bw0 = *(const short8*)(gbuf + (size_t)oct * 512 + lane * 8);
    short8 bw1 = *(const short8*)(gbuf + (size_t)(16 + oct) * 512 + lane * 8);
    acc2[oct] = __builtin_amdgcn_mfma_f32_16x16x32_bf16(aO0, bw0, acc2[oct], 0, 0, 0);
    acc2[oct] = __builtin_amdgcn_mfma_f32_16x16x32_bf16(aO1, bw1, acc2[oct], 0, 0, 0);
  }
  __syncthreads();
  // half 1: Wo frags 32..63 (kc 2,3)
  {
    const ushort_t* src = Wo_fb + 16384 + w * 8 * 512 + lane * 8;
    ushort_t* dst = gbuf + w * 8 * 512;
    #pragma unroll
    for (int b = 0; b < 8; ++b)
      gload_lds16(src + b * 512, dst + b * 512);
  }
  __syncthreads();
  #pragma unroll
  for (int oct = 0; oct < 16; ++oct) {
    short8 bw2 = *(const short8*)(gbuf + (size_t)oct * 512 + lane * 8);
    short8 bw3 = *(const short8*)(gbuf + (size_t)(16 + oct) * 512 + lane * 8);
    acc2[oct] = __builtin_amdgcn_mfma_f32_16x16x32_bf16(aO2, bw2, acc2[oct], 0, 0, 0);
    acc2[oct] = __builtin_amdgcn_mfma_f32_16x16x32_bf16(aO3, bw3, acc2[oct], 0, 0, 0);
  }
  __syncthreads();            // all waves done reading gbuf before outb write
  #pragma unroll
  for (int oct = 0; oct < 16; ++oct) {
    uint2v p2;
    p2[0] = pack_bfrh(acc2[oct][0], acc2[oct][1]);
    p2[1] = pack_bfrh(acc2[oct][2], acc2[oct][3]);
    *(uint2v*)(&outb[(oct * 16 + l16) * 68 + w * 16 + quad * 4]) = p2;
  }
  __syncthreads();
  // ---- residual + coalesced stores (64 cols) ----
  {
    const float gm = gamma_p[0];
    const int oc = (t >> 4);
    const int lch = (t & 15) * 4;
    #pragma unroll
    for (int ocg = 0; ocg < 16; ++ocg) {
      int row = ocg * 16 + oc;
      ushort4v ov = *(const ushort4v*)(&outb[row * 68 + lch]);
      const float* xp = x + ((size_t)n * 256 + row) * 4096 + l0 + lch;
      float* op = out + ((size_t)n * 256 + row) * 4096 + l0 + lch;
      float4 xv = *(const float4*)xp;
      float4 v;
      v.x = xv.x + gm * bf2f(ov[0]);
      v.y = xv.y + gm * bf2f(ov[1]);
      v.z = xv.z + gm * bf2f(ov[2]);
      v.w = xv.w + gm * bf2f(ov[3]);
      *(float4*)op = v;
    }
  }
}

extern "C" void kernel_launch(void* const* d_in, const int* in_sizes, int n_in,
                              void* d_out, int out_size, void* d_ws, size_t ws_size,
                              hipStream_t stream) {
  const float* x  = (const float*)d_in[0];
  const float* Wt = (const float*)d_in[1];
  const float* Wp = (const float*)d_in[2];
  const float* Wg = (const float*)d_in[3];
  const float* Wo = (const float*)d_in[4];
  const float* ut = (const float*)d_in[5];
  const float* up = (const float*)d_in[6];
  const float* ug = (const float*)d_in[7];
  const float* uo = (const float*)d_in[8];
  const float* gamma = (const float*)d_in[9];
  float* ws  = (float*)d_ws;
  float* out = (float*)d_out;

  ushort_t* wb      = (ushort_t*)(ws + WS_WB_F);
  ushort_t* Wo_b    = (ushort_t*)(ws + WS_WO_F);
  ushort_t* theta_b = (ushort_t*)(ws + WS_TH_F);
  ushort_t* phi_b   = (ushort_t*)(ws + WS_PH_F);
  ushort_t* g_fb    = (ushort_t*)(ws + WS_G_F);

  sn_kernel<<<4, 256, 0, stream>>>(Wt, Wp, Wg, Wo, ut, up, ug, uo, ws);
  proj_mfma<<<dim3(32, 16), 256, 0, stream>>>(x, wb, theta_b, phi_b, g_fb);
  attn_mfma<<<dim3(64, 16), 256, 0, stream>>>(x, theta_b, phi_b, g_fb, Wo_b, gamma, out);
}